// Round 12
// baseline (141.617 us; speedup 1.0000x reference)
//
#include <hip/hip_runtime.h>
#include <stdint.h>

typedef __bf16 bf16_t;
typedef bf16_t bf16x8 __attribute__((ext_vector_type(8)));
typedef float floatx4 __attribute__((ext_vector_type(4)));

#define HW 56
#define NTOK 6272   // 2*56*56

__device__ __forceinline__ uint16_t f2bf(float f){
  union { float f; uint32_t i; } c; c.f = f;
  uint32_t r = (c.i + 0x7FFFu + ((c.i >> 16) & 1u)) >> 16;
  return (uint16_t)r;
}
__device__ __forceinline__ float bflo(uint32_t u){
  union { uint32_t i; float f; } c; c.i = u << 16; return c.f;
}
__device__ __forceinline__ float bfhi(uint32_t u){
  union { uint32_t i; float f; } c; c.i = u & 0xffff0000u; return c.f;
}

// ---------- prep: fused x-convert + both weight transposes ----------
__global__ __launch_bounds__(256) void prep_kernel(
    const float* __restrict__ x,      uint16_t* __restrict__ xb,
    const float* __restrict__ w_qkv,  uint16_t* __restrict__ wqkvT,
    const float* __restrict__ w_proj, uint16_t* __restrict__ wprojT)
{
  __shared__ uint16_t tile[64][65];
  const int bx = blockIdx.x;
  const int t = threadIdx.x;
  if (bx < 784){
    int idx = bx * 256 + t;
    const float4* s = (const float4*)x + (size_t)idx * 2;
    float4 a = s[0], b = s[1];
    uint4 pk;
    pk.x = (uint32_t)f2bf(a.x) | ((uint32_t)f2bf(a.y) << 16);
    pk.y = (uint32_t)f2bf(a.z) | ((uint32_t)f2bf(a.w) << 16);
    pk.z = (uint32_t)f2bf(b.x) | ((uint32_t)f2bf(b.y) << 16);
    pk.w = (uint32_t)f2bf(b.z) | ((uint32_t)f2bf(b.w) << 16);
    ((uint4*)xb)[idx] = pk;
    return;
  }
  const float* src; uint16_t* dst; int N, q;
  if (bx < 832){ q = bx - 784; src = w_qkv;  dst = wqkvT;  N = 768; }
  else         { q = bx - 832; src = w_proj; dst = wprojT; N = 256; }
  const int k0 = (q & 3) * 64, n0 = (q >> 2) * 64;   // K=256 always
  for (int idx = t; idx < 64 * 64; idx += 256){
    int r = idx >> 6, c = idx & 63;
    tile[r][c] = f2bf(src[(k0 + r) * N + n0 + c]);
  }
  __syncthreads();
  for (int idx = t; idx < 64 * 64; idx += 256){
    int r = idx >> 6, c = idx & 63;
    dst[(n0 + r) * 256 + k0 + c] = tile[c][r];
  }
}

// ---------- GEMM: C[M,N] = A[M,256](bf16) * Bt[N,256]^T(bf16) + bias(fp32) ----------
// Tile 64 x NT, 4 waves. Register double-buffer over the two K-halves:
// ko=1 global loads are issued before the ko=0 MFMA loop so their latency
// overlaps compute (the 2-barrier structure otherwise exposes it fully).
// AHM: A is head-major [8][NTOK][32]; else row-major [M][256].
#define KDIM 256
#define KHALF 128
#define KP 136

template<int OUTF32, int AHM, int NT>
__global__ __launch_bounds__(256) void gemm_bt_bias(
    const uint16_t* __restrict__ A,
    const uint16_t* __restrict__ Bt,
    const float* __restrict__ bias,
    void* __restrict__ Cv,
    int N)
{
  constexpr int NF = NT / 32;            // B frags per wave
  constexpr int NCH = (64 + NT) * 16;    // 16B chunks per K-half
  constexpr int NR = NCH / 256;          // chunks per thread (12 @NT=128, 8 @NT=64)
  __shared__ uint16_t Al[64 * KP];
  __shared__ uint16_t Bl[NT * KP];
  const int m0 = blockIdx.x * 64, n0 = blockIdx.y * NT;
  const int t = threadIdx.x;
  const int lane = t & 63;
  const int wave = t >> 6;
  const int wm = (wave & 1) * 32;
  const int wn = (wave >> 1) * (NF * 16);
  const int fr = lane & 15;
  const int q8 = (lane >> 4) * 8;

  floatx4 acc[2][NF];
  #pragma unroll
  for (int mi = 0; mi < 2; mi++)
    #pragma unroll
    for (int nf = 0; nf < NF; nf++) acc[mi][nf] = (floatx4){0.f,0.f,0.f,0.f};

  uint4 regs[NR];

  auto load_half = [&](int ko){
    #pragma unroll
    for (int ii = 0; ii < NR; ii++){
      int ch = ii * 256 + t;
      if (ch < 1024){                    // A chunk
        int row = ch >> 4, col = (ch & 15) * 8;
        const uint16_t* ga;
        if (AHM){
          int d0 = ko * KHALF + col;     // chunk stays within one 32-dim head plane
          ga = A + (size_t)(d0 >> 5) * (NTOK * 32) + (m0 + row) * 32 + (d0 & 31);
        } else {
          ga = A + (m0 + row) * KDIM + ko * KHALF + col;
        }
        regs[ii] = *(const uint4*)ga;
      } else {                           // B chunk
        int idx = ch - 1024;
        int row = idx >> 4, col = (idx & 15) * 8;
        regs[ii] = *(const uint4*)(Bt + (n0 + row) * KDIM + ko * KHALF + col);
      }
    }
  };
  auto store_half = [&](){
    #pragma unroll
    for (int ii = 0; ii < NR; ii++){
      int ch = ii * 256 + t;
      if (ch < 1024){
        int row = ch >> 4, col = (ch & 15) * 8;
        *(uint4*)(Al + row * KP + col) = regs[ii];
      } else {
        int idx = ch - 1024;
        int row = idx >> 4, col = (idx & 15) * 8;
        *(uint4*)(Bl + row * KP + col) = regs[ii];
      }
    }
  };
  auto compute_half = [&](){
    #pragma unroll
    for (int kk = 0; kk < KHALF; kk += 32){
      bf16x8 a0 = *(const bf16x8*)(Al + (wm + fr)      * KP + kk + q8);
      bf16x8 a1 = *(const bf16x8*)(Al + (wm + 16 + fr) * KP + kk + q8);
      bf16x8 bfrag[NF];
      #pragma unroll
      for (int nf = 0; nf < NF; nf++)
        bfrag[nf] = *(const bf16x8*)(Bl + (wn + nf * 16 + fr) * KP + kk + q8);
      #pragma unroll
      for (int nf = 0; nf < NF; nf++){
        acc[0][nf] = __builtin_amdgcn_mfma_f32_16x16x32_bf16(a0, bfrag[nf], acc[0][nf], 0, 0, 0);
        acc[1][nf] = __builtin_amdgcn_mfma_f32_16x16x32_bf16(a1, bfrag[nf], acc[1][nf], 0, 0, 0);
      }
    }
  };

  load_half(0);
  store_half();
  __syncthreads();
  load_half(1);        // in flight during ko=0 compute
  compute_half();
  __syncthreads();     // everyone done reading LDS half 0
  store_half();        // waits vmcnt here (latency already overlapped)
  __syncthreads();
  compute_half();

  // epilogue: C/D layout col=lane&15, row=(lane>>4)*4+r  [verified m89/m91]
  const int ccol = lane & 15;
  const int crow = (lane >> 4) * 4;
  float bv[NF];
  #pragma unroll
  for (int nf = 0; nf < NF; nf++) bv[nf] = bias[n0 + wn + nf * 16 + ccol];
  #pragma unroll
  for (int mi = 0; mi < 2; mi++){
    #pragma unroll
    for (int r2 = 0; r2 < 4; r2++){
      int r = m0 + wm + mi * 16 + crow + r2;
      #pragma unroll
      for (int nf = 0; nf < NF; nf++){
        int cidx = r * N + n0 + wn + nf * 16 + ccol;
        if (OUTF32) ((float*)Cv)[cidx] = acc[mi][nf][r2] + bv[nf];
        else        ((uint16_t*)Cv)[cidx] = f2bf(acc[mi][nf][r2] + bv[nf]);
      }
    }
  }
}

// ---------- NATTEN attention v4.2: LDS-staged K/V tile (r11, unchanged) ----------
#define WIN 20
#define SLP 40   // 80 B slice stride: every b128 LDS access stays 16B-aligned

__global__ __launch_bounds__(256, 2) void natten_kernel(
    const uint16_t* __restrict__ qkv,   // [NTOK][768]
    const float* __restrict__ rpb0,     // [4][13][13]
    const float* __restrict__ rpb1,
    uint16_t* __restrict__ attnH)       // [8][NTOK][32]
{
  __shared__ uint16_t KS[400 * SLP];
  __shared__ uint16_t VS[400 * SLP];
  __shared__ float RPB[169];

  const int t = threadIdx.x;
  const int z = blockIdx.x;             // b*8 + h
  const int b = z >> 3, h = z & 7;
  const int j0 = blockIdx.y * 8, i0 = blockIdx.z * 8;
  const int split = h >> 2;
  const int dil = split + 1;
  const float* rpb = (split ? rpb1 : rpb0) + (h & 3) * 169;
  if (t < 169) RPB[t] = rpb[t];

  const int r0 = max(0, i0 - 3 * dil);
  const int c0 = max(0, j0 - 3 * dil);
  const int R  = min(55, i0 + 7 + 3 * dil) - r0 + 1;   // <= 20
  const int C  = min(55, j0 + 7 + 3 * dil) - c0 + 1;   // <= 20

  const int nchunk = R * WIN * 4;       // 16B chunks per array
  for (int ch = t; ch < nchunk; ch += 256){
    int tok = ch >> 2, q = ch & 3;
    int tr = tok / WIN;
    int tc = tok - tr * WIN;
    if (tc < C){                        // skip out-of-window cols (never read)
      const uint16_t* src = qkv + (size_t)((b * HW + r0 + tr) * HW + c0 + tc) * 768
                            + 256 + h * 32 + q * 8;
      int lds = tok * SLP + q * 8;
      *(bf16x8*)(KS + lds) = *(const bf16x8*)(src);
      *(bf16x8*)(VS + lds) = *(const bf16x8*)(src + 256);
    }
  }
  __syncthreads();

  const int c  = t & 3;
  const int qi = t >> 2;
  const int j = j0 + (qi & 7);
  const int i = i0 + (qi >> 3);

  const int ri = i % dil, pi = i / dil;
  const int rj = j % dil, pj = j / dil;
  const int Lri = (HW - ri + dil - 1) / dil;
  const int Lrj = (HW - rj + dil - 1) / dil;
  const int psi = min(max(pi - 3, 0), Lri - 7);
  const int psj = min(max(pj - 3, 0), Lrj - 7);
  const int bi0 = psi - pi + 6, bj0 = psj - pj + 6;
  const int ni0 = psi * dil + ri, nj0 = psj * dil + rj;

  const int tok = (b * HW + i) * HW + j;
  const float scale = 0.17677669529663687f;

  float qv[8];
  {
    uint4 u = *(const uint4*)(qkv + (size_t)tok * 768 + h * 32 + c * 8);
    qv[0] = bflo(u.x) * scale; qv[1] = bfhi(u.x) * scale;
    qv[2] = bflo(u.y) * scale; qv[3] = bfhi(u.y) * scale;
    qv[4] = bflo(u.z) * scale; qv[5] = bfhi(u.z) * scale;
    qv[6] = bflo(u.w) * scale; qv[7] = bfhi(u.w) * scale;
  }

  const int lbase = (ni0 - r0) * WIN + (nj0 - c0);
  float lgl[13];
  lgl[12] = -1e30f;
  #pragma unroll
  for (int ai = 0; ai < 7; ai++){
    int lrow = lbase + ai * dil * WIN;
    int rpi = (bi0 + ai) * 13 + bj0;
    #pragma unroll
    for (int aj = 0; aj < 7; aj++){
      const int a = ai * 7 + aj;
      uint4 u = *(const uint4*)(KS + (lrow + aj * dil) * SLP + c * 8);
      float d = qv[0] * bflo(u.x) + qv[1] * bfhi(u.x)
              + qv[2] * bflo(u.y) + qv[3] * bfhi(u.y)
              + qv[4] * bflo(u.z) + qv[5] * bfhi(u.z)
              + qv[6] * bflo(u.w) + qv[7] * bfhi(u.w);
      d += __shfl_xor(d, 1);
      d += __shfl_xor(d, 2);
      d += RPB[rpi + aj];
      if ((a & 3) == c) lgl[a >> 2] = d;
    }
  }

  float mx = lgl[0];
  #pragma unroll
  for (int s = 1; s < 13; s++) mx = fmaxf(mx, lgl[s]);
  mx = fmaxf(mx, __shfl_xor(mx, 1));
  mx = fmaxf(mx, __shfl_xor(mx, 2));
  float ssum = 0.f;
  #pragma unroll
  for (int s = 0; s < 13; s++){
    float e = __expf(lgl[s] - mx);
    lgl[s] = e;
    ssum += e;
  }
  ssum += __shfl_xor(ssum, 1);
  ssum += __shfl_xor(ssum, 2);
  float inv = 1.0f / ssum;

  float ov[8];
  #pragma unroll
  for (int d = 0; d < 8; d++) ov[d] = 0.f;

  const int lane4 = t & 60;
  #pragma unroll
  for (int ai = 0; ai < 7; ai++){
    int lrow = lbase + ai * dil * WIN;
    #pragma unroll
    for (int aj = 0; aj < 7; aj++){
      const int a = ai * 7 + aj;
      uint4 u = *(const uint4*)(VS + (lrow + aj * dil) * SLP + c * 8);
      float w = __shfl(lgl[a >> 2], lane4 | (a & 3)) * inv;
      ov[0] += w * bflo(u.x); ov[1] += w * bfhi(u.x);
      ov[2] += w * bflo(u.y); ov[3] += w * bfhi(u.y);
      ov[4] += w * bflo(u.z); ov[5] += w * bfhi(u.z);
      ov[6] += w * bflo(u.w); ov[7] += w * bfhi(u.w);
    }
  }

  uint4 pk;
  pk.x = (uint32_t)f2bf(ov[0]) | ((uint32_t)f2bf(ov[1]) << 16);
  pk.y = (uint32_t)f2bf(ov[2]) | ((uint32_t)f2bf(ov[3]) << 16);
  pk.z = (uint32_t)f2bf(ov[4]) | ((uint32_t)f2bf(ov[5]) << 16);
  pk.w = (uint32_t)f2bf(ov[6]) | ((uint32_t)f2bf(ov[7]) << 16);
  *(uint4*)(attnH + ((size_t)h * NTOK + tok) * 32 + c * 8) = pk;
}

extern "C" void kernel_launch(void* const* d_in, const int* in_sizes, int n_in,
                              void* d_out, int out_size, void* d_ws, size_t ws_size,
                              hipStream_t stream)
{
  (void)in_sizes; (void)n_in; (void)out_size; (void)ws_size;
  const float* x      = (const float*)d_in[0];
  const float* w_qkv  = (const float*)d_in[1];
  const float* b_qkv  = (const float*)d_in[2];
  const float* w_proj = (const float*)d_in[3];
  const float* b_proj = (const float*)d_in[4];
  const float* rpb0   = (const float*)d_in[5];
  const float* rpb1   = (const float*)d_in[6];
  float* out = (float*)d_out;

  uint16_t* wqkvT  = (uint16_t*)d_ws;                    // 768*256
  uint16_t* wprojT = wqkvT + 768 * 256;                  // 256*256
  uint16_t* xb     = wprojT + 256 * 256;                 // NTOK*256
  uint16_t* qkv    = xb + (size_t)NTOK * 256;            // NTOK*768
  uint16_t* attn   = qkv + (size_t)NTOK * 768;           // 8*NTOK*32 (head-major)

  prep_kernel<<<dim3(848), 256, 0, stream>>>(x, xb, w_qkv, wqkvT, w_proj, wprojT);
  gemm_bt_bias<0,0,128><<<dim3(98, 6), 256, 0, stream>>>(xb, wqkvT, b_qkv, qkv, 768);
  natten_kernel<<<dim3(16, 7, 7), 256, 0, stream>>>(qkv, rpb0, rpb1, attn);
  gemm_bt_bias<1,1,64><<<dim3(98, 4), 256, 0, stream>>>(attn, wprojT, b_proj, out, 256);
}

// Round 13
// 116.563 us; speedup vs baseline: 1.2149x; 1.2149x over previous
//
#include <hip/hip_runtime.h>
#include <stdint.h>

typedef __bf16 bf16_t;
typedef bf16_t bf16x8 __attribute__((ext_vector_type(8)));
typedef float floatx4 __attribute__((ext_vector_type(4)));

#define HW 56
#define NTOK 6272   // 2*56*56

__device__ __forceinline__ uint16_t f2bf(float f){
  union { float f; uint32_t i; } c; c.f = f;
  uint32_t r = (c.i + 0x7FFFu + ((c.i >> 16) & 1u)) >> 16;
  return (uint16_t)r;
}
__device__ __forceinline__ float bflo(uint32_t u){
  union { uint32_t i; float f; } c; c.i = u << 16; return c.f;
}
__device__ __forceinline__ float bfhi(uint32_t u){
  union { uint32_t i; float f; } c; c.i = u & 0xffff0000u; return c.f;
}

// ---------- prep: fused x-convert + both weight transposes ----------
__global__ __launch_bounds__(256) void prep_kernel(
    const float* __restrict__ x,      uint16_t* __restrict__ xb,
    const float* __restrict__ w_qkv,  uint16_t* __restrict__ wqkvT,
    const float* __restrict__ w_proj, uint16_t* __restrict__ wprojT)
{
  __shared__ uint16_t tile[64][65];
  const int bx = blockIdx.x;
  const int t = threadIdx.x;
  if (bx < 784){
    int idx = bx * 256 + t;
    const float4* s = (const float4*)x + (size_t)idx * 2;
    float4 a = s[0], b = s[1];
    uint4 pk;
    pk.x = (uint32_t)f2bf(a.x) | ((uint32_t)f2bf(a.y) << 16);
    pk.y = (uint32_t)f2bf(a.z) | ((uint32_t)f2bf(a.w) << 16);
    pk.z = (uint32_t)f2bf(b.x) | ((uint32_t)f2bf(b.y) << 16);
    pk.w = (uint32_t)f2bf(b.z) | ((uint32_t)f2bf(b.w) << 16);
    ((uint4*)xb)[idx] = pk;
    return;
  }
  const float* src; uint16_t* dst; int N, q;
  if (bx < 832){ q = bx - 784; src = w_qkv;  dst = wqkvT;  N = 768; }
  else         { q = bx - 832; src = w_proj; dst = wprojT; N = 256; }
  const int k0 = (q & 3) * 64, n0 = (q >> 2) * 64;   // K=256 always
  for (int idx = t; idx < 64 * 64; idx += 256){
    int r = idx >> 6, c = idx & 63;
    tile[r][c] = f2bf(src[(k0 + r) * N + n0 + c]);
  }
  __syncthreads();
  for (int idx = t; idx < 64 * 64; idx += 256){
    int r = idx >> 6, c = idx & 63;
    dst[(n0 + r) * 256 + k0 + c] = tile[c][r];
  }
}

// ---------- GEMM: C[M,N] = A[M,256](bf16) * Bt[N,256]^T(bf16) + bias(fp32) ----------
// Tile 64 x NT. 4 waves: wave w -> rows (w&1)*32, cols (w>>1)*(NT/2).
// AHM: A is head-major [8][NTOK][32]; else row-major [M][256].
// NOTE r12: register double-buffering of the K-halves REGRESSED (117->142 us;
// 48 held VGPRs through the MFMA loop + extra barrier) — keep the simple
// 2-stage structure.
#define KDIM 256
#define KHALF 128
#define KP 136

template<int OUTF32, int AHM, int NT>
__global__ __launch_bounds__(256) void gemm_bt_bias(
    const uint16_t* __restrict__ A,
    const uint16_t* __restrict__ Bt,
    const float* __restrict__ bias,
    void* __restrict__ Cv,
    int N)
{
  constexpr int NF = NT / 32;            // B frags per wave (2 or 4)
  __shared__ uint16_t Al[64 * KP];
  __shared__ uint16_t Bl[NT * KP];
  const int m0 = blockIdx.x * 64, n0 = blockIdx.y * NT;
  const int t = threadIdx.x;
  const int lane = t & 63;
  const int wave = t >> 6;
  const int wm = (wave & 1) * 32;
  const int wn = (wave >> 1) * (NF * 16);
  const int fr = lane & 15;
  const int q8 = (lane >> 4) * 8;

  floatx4 acc[2][NF];
  #pragma unroll
  for (int mi = 0; mi < 2; mi++)
    #pragma unroll
    for (int nf = 0; nf < NF; nf++) acc[mi][nf] = (floatx4){0.f,0.f,0.f,0.f};

  constexpr int NCH = (64 + NT) * 16;    // 16B chunks per ko half

  for (int ko = 0; ko < 2; ko++){
    if (ko) __syncthreads();
    #pragma unroll
    for (int ch0 = 0; ch0 < NCH; ch0 += 256){
      int ch = ch0 + t;
      if (ch < 1024){                    // A chunk
        int row = ch >> 4, col = (ch & 15) * 8;
        const uint16_t* ga;
        if (AHM){
          int d0 = ko * KHALF + col;     // chunk stays within one 32-dim head plane
          ga = A + (size_t)(d0 >> 5) * (NTOK * 32) + (m0 + row) * 32 + (d0 & 31);
        } else {
          ga = A + (m0 + row) * KDIM + ko * KHALF + col;
        }
        *(bf16x8*)(Al + row * KP + col) = *(const bf16x8*)ga;
      } else {                           // B chunk
        int idx = ch - 1024;
        int row = idx >> 4, col = (idx & 15) * 8;
        *(bf16x8*)(Bl + row * KP + col) =
            *(const bf16x8*)(Bt + (n0 + row) * KDIM + ko * KHALF + col);
      }
    }
    __syncthreads();
    #pragma unroll
    for (int kk = 0; kk < KHALF; kk += 32){
      bf16x8 a0 = *(const bf16x8*)(Al + (wm + fr)      * KP + kk + q8);
      bf16x8 a1 = *(const bf16x8*)(Al + (wm + 16 + fr) * KP + kk + q8);
      bf16x8 bfrag[NF];
      #pragma unroll
      for (int nf = 0; nf < NF; nf++)
        bfrag[nf] = *(const bf16x8*)(Bl + (wn + nf * 16 + fr) * KP + kk + q8);
      #pragma unroll
      for (int nf = 0; nf < NF; nf++){
        acc[0][nf] = __builtin_amdgcn_mfma_f32_16x16x32_bf16(a0, bfrag[nf], acc[0][nf], 0, 0, 0);
        acc[1][nf] = __builtin_amdgcn_mfma_f32_16x16x32_bf16(a1, bfrag[nf], acc[1][nf], 0, 0, 0);
      }
    }
  }

  // epilogue: C/D layout col=lane&15, row=(lane>>4)*4+r  [verified m89/m91]
  const int ccol = lane & 15;
  const int crow = (lane >> 4) * 4;
  float bv[NF];
  #pragma unroll
  for (int nf = 0; nf < NF; nf++) bv[nf] = bias[n0 + wn + nf * 16 + ccol];
  #pragma unroll
  for (int mi = 0; mi < 2; mi++){
    #pragma unroll
    for (int r2 = 0; r2 < 4; r2++){
      int r = m0 + wm + mi * 16 + crow + r2;
      #pragma unroll
      for (int nf = 0; nf < NF; nf++){
        int cidx = r * N + n0 + wn + nf * 16 + ccol;
        if (OUTF32) ((float*)Cv)[cidx] = acc[mi][nf][r2] + bv[nf];
        else        ((uint16_t*)Cv)[cidx] = f2bf(acc[mi][nf][r2] + bv[nf]);
      }
    }
  }
}

// ---------- NATTEN attention v4.2: LDS-staged K/V tile ----------
#define WIN 20
#define SLP 40   // 80 B slice stride: every b128 LDS access stays 16B-aligned

__global__ __launch_bounds__(256, 2) void natten_kernel(
    const uint16_t* __restrict__ qkv,   // [NTOK][768]
    const float* __restrict__ rpb0,     // [4][13][13]
    const float* __restrict__ rpb1,
    uint16_t* __restrict__ attnH)       // [8][NTOK][32]
{
  __shared__ uint16_t KS[400 * SLP];
  __shared__ uint16_t VS[400 * SLP];
  __shared__ float RPB[169];

  const int t = threadIdx.x;
  const int z = blockIdx.x;             // b*8 + h
  const int b = z >> 3, h = z & 7;
  const int j0 = blockIdx.y * 8, i0 = blockIdx.z * 8;
  const int split = h >> 2;
  const int dil = split + 1;
  const float* rpb = (split ? rpb1 : rpb0) + (h & 3) * 169;
  if (t < 169) RPB[t] = rpb[t];

  const int r0 = max(0, i0 - 3 * dil);
  const int c0 = max(0, j0 - 3 * dil);
  const int R  = min(55, i0 + 7 + 3 * dil) - r0 + 1;   // <= 20
  const int C  = min(55, j0 + 7 + 3 * dil) - c0 + 1;   // <= 20

  const int nchunk = R * WIN * 4;       // 16B chunks per array
  for (int ch = t; ch < nchunk; ch += 256){
    int tok = ch >> 2, q = ch & 3;
    int tr = tok / WIN;
    int tc = tok - tr * WIN;
    if (tc < C){                        // skip out-of-window cols (never read)
      const uint16_t* src = qkv + (size_t)((b * HW + r0 + tr) * HW + c0 + tc) * 768
                            + 256 + h * 32 + q * 8;
      int lds = tok * SLP + q * 8;
      *(bf16x8*)(KS + lds) = *(const bf16x8*)(src);
      *(bf16x8*)(VS + lds) = *(const bf16x8*)(src + 256);
    }
  }
  __syncthreads();

  const int c  = t & 3;
  const int qi = t >> 2;
  const int j = j0 + (qi & 7);
  const int i = i0 + (qi >> 3);

  const int ri = i % dil, pi = i / dil;
  const int rj = j % dil, pj = j / dil;
  const int Lri = (HW - ri + dil - 1) / dil;
  const int Lrj = (HW - rj + dil - 1) / dil;
  const int psi = min(max(pi - 3, 0), Lri - 7);
  const int psj = min(max(pj - 3, 0), Lrj - 7);
  const int bi0 = psi - pi + 6, bj0 = psj - pj + 6;
  const int ni0 = psi * dil + ri, nj0 = psj * dil + rj;

  const int tok = (b * HW + i) * HW + j;
  const float scale = 0.17677669529663687f;

  float qv[8];
  {
    uint4 u = *(const uint4*)(qkv + (size_t)tok * 768 + h * 32 + c * 8);
    qv[0] = bflo(u.x) * scale; qv[1] = bfhi(u.x) * scale;
    qv[2] = bflo(u.y) * scale; qv[3] = bfhi(u.y) * scale;
    qv[4] = bflo(u.z) * scale; qv[5] = bfhi(u.z) * scale;
    qv[6] = bflo(u.w) * scale; qv[7] = bfhi(u.w) * scale;
  }

  const int lbase = (ni0 - r0) * WIN + (nj0 - c0);
  float lgl[13];
  lgl[12] = -1e30f;
  #pragma unroll
  for (int ai = 0; ai < 7; ai++){
    int lrow = lbase + ai * dil * WIN;
    int rpi = (bi0 + ai) * 13 + bj0;
    #pragma unroll
    for (int aj = 0; aj < 7; aj++){
      const int a = ai * 7 + aj;
      uint4 u = *(const uint4*)(KS + (lrow + aj * dil) * SLP + c * 8);
      float d = qv[0] * bflo(u.x) + qv[1] * bfhi(u.x)
              + qv[2] * bflo(u.y) + qv[3] * bfhi(u.y)
              + qv[4] * bflo(u.z) + qv[5] * bfhi(u.z)
              + qv[6] * bflo(u.w) + qv[7] * bfhi(u.w);
      d += __shfl_xor(d, 1);
      d += __shfl_xor(d, 2);
      d += RPB[rpi + aj];
      if ((a & 3) == c) lgl[a >> 2] = d;
    }
  }

  float mx = lgl[0];
  #pragma unroll
  for (int s = 1; s < 13; s++) mx = fmaxf(mx, lgl[s]);
  mx = fmaxf(mx, __shfl_xor(mx, 1));
  mx = fmaxf(mx, __shfl_xor(mx, 2));
  float ssum = 0.f;
  #pragma unroll
  for (int s = 0; s < 13; s++){
    float e = __expf(lgl[s] - mx);
    lgl[s] = e;
    ssum += e;
  }
  ssum += __shfl_xor(ssum, 1);
  ssum += __shfl_xor(ssum, 2);
  float inv = 1.0f / ssum;

  float ov[8];
  #pragma unroll
  for (int d = 0; d < 8; d++) ov[d] = 0.f;

  const int lane4 = t & 60;
  #pragma unroll
  for (int ai = 0; ai < 7; ai++){
    int lrow = lbase + ai * dil * WIN;
    #pragma unroll
    for (int aj = 0; aj < 7; aj++){
      const int a = ai * 7 + aj;
      uint4 u = *(const uint4*)(VS + (lrow + aj * dil) * SLP + c * 8);
      float w = __shfl(lgl[a >> 2], lane4 | (a & 3)) * inv;
      ov[0] += w * bflo(u.x); ov[1] += w * bfhi(u.x);
      ov[2] += w * bflo(u.y); ov[3] += w * bfhi(u.y);
      ov[4] += w * bflo(u.z); ov[5] += w * bfhi(u.z);
      ov[6] += w * bflo(u.w); ov[7] += w * bfhi(u.w);
    }
  }

  uint4 pk;
  pk.x = (uint32_t)f2bf(ov[0]) | ((uint32_t)f2bf(ov[1]) << 16);
  pk.y = (uint32_t)f2bf(ov[2]) | ((uint32_t)f2bf(ov[3]) << 16);
  pk.z = (uint32_t)f2bf(ov[4]) | ((uint32_t)f2bf(ov[5]) << 16);
  pk.w = (uint32_t)f2bf(ov[6]) | ((uint32_t)f2bf(ov[7]) << 16);
  *(uint4*)(attnH + ((size_t)h * NTOK + tok) * 32 + c * 8) = pk;
}

extern "C" void kernel_launch(void* const* d_in, const int* in_sizes, int n_in,
                              void* d_out, int out_size, void* d_ws, size_t ws_size,
                              hipStream_t stream)
{
  (void)in_sizes; (void)n_in; (void)out_size; (void)ws_size;
  const float* x      = (const float*)d_in[0];
  const float* w_qkv  = (const float*)d_in[1];
  const float* b_qkv  = (const float*)d_in[2];
  const float* w_proj = (const float*)d_in[3];
  const float* b_proj = (const float*)d_in[4];
  const float* rpb0   = (const float*)d_in[5];
  const float* rpb1   = (const float*)d_in[6];
  float* out = (float*)d_out;

  uint16_t* wqkvT  = (uint16_t*)d_ws;                    // 768*256
  uint16_t* wprojT = wqkvT + 768 * 256;                  // 256*256
  uint16_t* xb     = wprojT + 256 * 256;                 // NTOK*256
  uint16_t* qkv    = xb + (size_t)NTOK * 256;            // NTOK*768
  uint16_t* attn   = qkv + (size_t)NTOK * 768;           // 8*NTOK*32 (head-major)

  prep_kernel<<<dim3(848), 256, 0, stream>>>(x, xb, w_qkv, wqkvT, w_proj, wprojT);
  gemm_bt_bias<0,0,128><<<dim3(98, 6), 256, 0, stream>>>(xb, wqkvT, b_qkv, qkv, 768);
  natten_kernel<<<dim3(16, 7, 7), 256, 0, stream>>>(qkv, rpb0, rpb1, attn);
  gemm_bt_bias<1,1,64><<<dim3(98, 4), 256, 0, stream>>>(attn, wprojT, b_proj, out, 256);
}